// Round 1
// baseline (3189.580 us; speedup 1.0000x reference)
//
#include <hip/hip_runtime.h>
#include <stdint.h>

#define DDIM 768
#define BROWS 4096
#define S0N 4096
#define DICT 32768
#define KTOT 262144u
#define PREF 2.0f
#define DELTA 4e-3f
#define CAND_CAP 16777216u
#define BAND_CAP 4096

// workspace layout (bytes)
static constexpr size_t OFF_L0   = 0;            // 4096*4096*4  = 64 MiB
static constexpr size_t OFF_XC   = 67108864;     // 4096*768*4   = 12 MiB
static constexpr size_t OFF_WDT  = 79691776;     // 32768*768*4  = 96 MiB
static constexpr size_t OFF_CTRL = 180355072;    // 128 KiB control block
static constexpr size_t OFF_ROWC = 180486144;    // 4096*4       = 16 KiB
static constexpr size_t OFF_ROWD = 180502528;    // 4096*256*8   = 8 MiB
static constexpr size_t OFF_CAND = 188891136;    // 16M*8        = 128 MiB
static constexpr size_t WS_NEED  = 323108864;

// ctrl u32 layout: [0]=cand_cnt [1]=binT [2]=c1 [3]=H [4]=c_hi [5]=band_cnt [6]=k_rem
// hist1 @ ctrl+256 (2048), hist2 @ ctrl+2304 (4096), band_idx @ ctrl+6400 (4096)
// band_v64 (double[4096]) @ OFF_CTRL+65536 ; extra (uint2[4096]) @ OFF_CTRL+98304

__device__ __forceinline__ unsigned umin_(unsigned a, unsigned b) { return a < b ? a : b; }
__device__ __forceinline__ float relu_(float v) { return v > 0.f ? v : 0.f; }

// ---------------- xc = x - b_dec ----------------
__global__ void k_prep_xc(const float* __restrict__ x, const float* __restrict__ b_dec,
                          float* __restrict__ xc) {
    int i = blockIdx.x * 256 + threadIdx.x;           // float4 index, exact grid
    float4 xv = ((const float4*)x)[i];
    int d = (i % (DDIM / 4)) * 4;
    float4 bv = *(const float4*)(b_dec + d);
    float4 o;
    o.x = xv.x - bv.x; o.y = xv.y - bv.y; o.z = xv.z - bv.z; o.w = xv.w - bv.w;
    ((float4*)xc)[i] = o;
}

// ---------------- WdT[j][d] = Wd[d][j] ----------------
__global__ void k_transpose(const float* __restrict__ Wd, float* __restrict__ WdT) {
    __shared__ float tile[32][33];
    int j0 = blockIdx.x * 32, d0 = blockIdx.y * 32;
    int tx = threadIdx.x & 31, ty = threadIdx.x >> 5;   // 32 x 8
#pragma unroll
    for (int i = 0; i < 4; ++i)
        tile[ty + i * 8][tx] = Wd[(size_t)(d0 + ty + i * 8) * DICT + j0 + tx];
    __syncthreads();
#pragma unroll
    for (int i = 0; i < 4; ++i)
        WdT[(size_t)(j0 + ty + i * 8) * DDIM + d0 + tx] = tile[tx][ty + i * 8];
}

// ---------------- f32 GEMM: C = relu(A @ W^T + bias) [, gate & candidate-append] ----------------
// A [4096,768], W [N,768]; 128x128 tile, BK=16, 256 threads, 8x8 per thread.
template<int EPI>
__launch_bounds__(256, 2) __global__
void k_gemm(const float* __restrict__ A, const float* __restrict__ W,
            const float* __restrict__ bias, float* __restrict__ l0buf,
            uint2* __restrict__ cand, unsigned* __restrict__ ctrl) {
    __shared__ float As[16][128];
    __shared__ float Bs[16][128];
    __shared__ unsigned pscan[256];
    __shared__ unsigned basev;

    const int t = threadIdx.x;
    const int tx = t & 15, ty = t >> 4;
    const int bm = blockIdx.y << 7;
    const int bn = blockIdx.x << 7;
    const int r0 = t >> 2;             // 0..63
    const int r1 = r0 + 64;
    const int kc = (t & 3) << 2;       // 0,4,8,12

    const float* Ab = A + (size_t)bm * DDIM;
    const float* Wb = W + (size_t)bn * DDIM;

    float acc[8][8];
#pragma unroll
    for (int i = 0; i < 8; ++i)
#pragma unroll
        for (int j = 0; j < 8; ++j) acc[i][j] = 0.f;

    float4 pa0 = *(const float4*)(Ab + (size_t)r0 * DDIM + kc);
    float4 pa1 = *(const float4*)(Ab + (size_t)r1 * DDIM + kc);
    float4 pb0 = *(const float4*)(Wb + (size_t)r0 * DDIM + kc);
    float4 pb1 = *(const float4*)(Wb + (size_t)r1 * DDIM + kc);

    for (int kt = 0; kt < 48; ++kt) {
        __syncthreads();
        As[kc + 0][r0] = pa0.x; As[kc + 1][r0] = pa0.y; As[kc + 2][r0] = pa0.z; As[kc + 3][r0] = pa0.w;
        As[kc + 0][r1] = pa1.x; As[kc + 1][r1] = pa1.y; As[kc + 2][r1] = pa1.z; As[kc + 3][r1] = pa1.w;
        Bs[kc + 0][r0] = pb0.x; Bs[kc + 1][r0] = pb0.y; Bs[kc + 2][r0] = pb0.z; Bs[kc + 3][r0] = pb0.w;
        Bs[kc + 0][r1] = pb1.x; Bs[kc + 1][r1] = pb1.y; Bs[kc + 2][r1] = pb1.z; Bs[kc + 3][r1] = pb1.w;
        __syncthreads();
        if (kt + 1 < 48) {
            int k0 = (kt + 1) << 4;
            pa0 = *(const float4*)(Ab + (size_t)r0 * DDIM + k0 + kc);
            pa1 = *(const float4*)(Ab + (size_t)r1 * DDIM + k0 + kc);
            pb0 = *(const float4*)(Wb + (size_t)r0 * DDIM + k0 + kc);
            pb1 = *(const float4*)(Wb + (size_t)r1 * DDIM + k0 + kc);
        }
#pragma unroll
        for (int kk = 0; kk < 16; ++kk) {
            const float4 a0 = *(const float4*)(&As[kk][tx << 2]);
            const float4 a1 = *(const float4*)(&As[kk][(tx << 2) + 64]);
            const float4 b0 = *(const float4*)(&Bs[kk][ty << 2]);
            const float4 b1 = *(const float4*)(&Bs[kk][(ty << 2) + 64]);
            const float av[8] = {a0.x, a0.y, a0.z, a0.w, a1.x, a1.y, a1.z, a1.w};
            const float bv[8] = {b0.x, b0.y, b0.z, b0.w, b1.x, b1.y, b1.z, b1.w};
#pragma unroll
            for (int i = 0; i < 8; ++i)
#pragma unroll
                for (int j = 0; j < 8; ++j)
                    acc[i][j] = fmaf(av[i], bv[j], acc[i][j]);
        }
    }

    if constexpr (EPI == 0) {
        // l0 = relu(acc + bias), store [4096]
#pragma unroll
        for (int i = 0; i < 8; ++i) {
            int row = bm + (tx << 2) + (i & 3) + ((i >> 2) << 6);
            float* orow = l0buf + (size_t)row * S0N;
            int cb = bn + (ty << 2);
            float4 z0 = *(const float4*)(bias + cb);
            float4 z1 = *(const float4*)(bias + cb + 64);
            float4 o0, o1;
            o0.x = relu_(acc[i][0] + z0.x); o0.y = relu_(acc[i][1] + z0.y);
            o0.z = relu_(acc[i][2] + z0.z); o0.w = relu_(acc[i][3] + z0.w);
            o1.x = relu_(acc[i][4] + z1.x); o1.y = relu_(acc[i][5] + z1.y);
            o1.z = relu_(acc[i][6] + z1.z); o1.w = relu_(acc[i][7] + z1.w);
            *(float4*)(orow + cb) = o0;
            *(float4*)(orow + cb + 64) = o1;
        }
    } else {
        // v = relu(acc + b1) * l0[row][col>>3]; append (v,idx) for v >= PREF
        unsigned cnt = 0;
#pragma unroll
        for (int i = 0; i < 8; ++i) {
            int row = bm + (tx << 2) + (i & 3) + ((i >> 2) << 6);
            const float* g = l0buf + (size_t)row * S0N;
#pragma unroll
            for (int j = 0; j < 8; ++j) {
                int col = bn + (ty << 2) + (j & 3) + ((j >> 2) << 6);
                float v = relu_(acc[i][j] + bias[col]);
                v *= g[col >> 3];
                acc[i][j] = v;
                cnt += (v >= PREF) ? 1u : 0u;
            }
        }
        pscan[t] = cnt;
        __syncthreads();
        for (int s = 1; s < 256; s <<= 1) {
            unsigned v2 = (t >= s) ? pscan[t - s] : 0u;
            __syncthreads();
            pscan[t] += v2;
            __syncthreads();
        }
        if (t == 255) basev = atomicAdd(&ctrl[0], pscan[255]);
        __syncthreads();
        unsigned off = basev + pscan[t] - cnt;
#pragma unroll
        for (int i = 0; i < 8; ++i) {
            int row = bm + (tx << 2) + (i & 3) + ((i >> 2) << 6);
#pragma unroll
            for (int j = 0; j < 8; ++j) {
                float v = acc[i][j];
                if (v >= PREF) {
                    int col = bn + (ty << 2) + (j & 3) + ((j >> 2) << 6);
                    if (off < CAND_CAP)
                        cand[off] = make_uint2(__float_as_uint(v),
                                               ((unsigned)row << 15) | (unsigned)col);
                    ++off;
                }
            }
        }
    }
}

// ---------------- selection: histograms over candidate float bits ----------------
__global__ void k_hist1(const uint2* __restrict__ cand, unsigned* __restrict__ ctrl) {
    __shared__ unsigned h[2048];
    for (int i = threadIdx.x; i < 2048; i += 256) h[i] = 0;
    __syncthreads();
    unsigned n = umin_(ctrl[0], CAND_CAP);
    for (unsigned i = blockIdx.x * 256 + threadIdx.x; i < n; i += gridDim.x * 256)
        atomicAdd(&h[cand[i].x >> 20], 1u);
    __syncthreads();
    unsigned* hist = ctrl + 256;
    for (int i = threadIdx.x; i < 2048; i += 256)
        if (h[i]) atomicAdd(&hist[i], h[i]);
}

__global__ void k_scan1(unsigned* __restrict__ ctrl) {
    __shared__ unsigned hs[2048];
    __shared__ unsigned cs[256];
    const unsigned* h = ctrl + 256;
    int t = threadIdx.x;
    for (int i = t; i < 2048; i += 256) hs[i] = h[i];
    __syncthreads();
    unsigned s = 0;
    for (int b = 0; b < 8; ++b) s += hs[t * 8 + b];
    cs[t] = s;
    __syncthreads();
    if (t == 0) {
        unsigned cum = 0, T = 0, cb = 0;
        for (int c = 255; c >= 0; --c) {
            if (cum + cs[c] >= KTOT) {
                for (int b = c * 8 + 7; b >= c * 8; --b) {
                    cum += hs[b];
                    if (cum >= KTOT) { T = (unsigned)b; cb = cum - hs[b]; break; }
                }
                break;
            }
            cum += cs[c];
        }
        ctrl[1] = T; ctrl[2] = cb;
    }
}

__global__ void k_hist2(const uint2* __restrict__ cand, unsigned* __restrict__ ctrl) {
    unsigned n = umin_(ctrl[0], CAND_CAP);
    unsigned T = ctrl[1];
    unsigned* hist2 = ctrl + 2304;
    for (unsigned i = blockIdx.x * 256 + threadIdx.x; i < n; i += gridDim.x * 256) {
        unsigned u = cand[i].x;
        if ((u >> 20) == T) atomicAdd(&hist2[(u >> 8) & 0xFFFu], 1u);
    }
}

__global__ void k_scan2(unsigned* __restrict__ ctrl) {
    __shared__ unsigned hs[4096];
    __shared__ unsigned cs[256];
    const unsigned* h = ctrl + 2304;
    int t = threadIdx.x;
    for (int i = t; i < 4096; i += 256) hs[i] = h[i];
    __syncthreads();
    unsigned s = 0;
    for (int b = 0; b < 16; ++b) s += hs[t * 16 + b];
    cs[t] = s;
    __syncthreads();
    if (t == 0) {
        unsigned cum = ctrl[2], T2 = 0;
        for (int c = 255; c >= 0; --c) {
            if (cum + cs[c] >= KTOT) {
                for (int b = c * 16 + 15; b >= c * 16; --b) {
                    cum += hs[b];
                    if (cum >= KTOT) { T2 = (unsigned)b; break; }
                }
                break;
            }
            cum += cs[c];
        }
        ctrl[3] = (ctrl[1] << 12) | T2;   // 24-bit prefix H
    }
}

// count strictly-above band, collect band members
__global__ void k_band(const uint2* __restrict__ cand, unsigned* __restrict__ ctrl) {
    __shared__ unsigned lhi;
    if (threadIdx.x == 0) lhi = 0;
    __syncthreads();
    unsigned n = umin_(ctrl[0], CAND_CAP);
    unsigned H = ctrl[3];
    float lo = __uint_as_float(H << 8) - DELTA;
    float hi = __uint_as_float((H + 1u) << 8) + DELTA;
    unsigned* band_idx = ctrl + 6400;
    unsigned my = 0;
    for (unsigned i = blockIdx.x * 256 + threadIdx.x; i < n; i += gridDim.x * 256) {
        float v = __uint_as_float(cand[i].x);
        if (v > hi) ++my;
        else if (v >= lo) {
            unsigned p = atomicAdd(&ctrl[5], 1u);
            if (p < BAND_CAP) band_idx[p] = cand[i].y;
        }
    }
    atomicAdd(&lhi, my);
    __syncthreads();
    if (threadIdx.x == 0 && lhi) atomicAdd(&ctrl[4], lhi);
}

// f64 recompute of band elements (exact-vs-numpy selection values)
__global__ void k_f64(const float* __restrict__ x, const float* __restrict__ b_dec,
                      const float* __restrict__ W0, const float* __restrict__ b0,
                      const float* __restrict__ W1, const float* __restrict__ b1,
                      const unsigned* __restrict__ ctrl, double* __restrict__ band_v) {
    unsigned n = umin_(ctrl[5], BAND_CAP);
    unsigned bi = blockIdx.x;
    if (bi >= n) return;
    const unsigned* band_idx = ctrl + 6400;
    unsigned idx = band_idx[bi];
    int b = idx >> 15, j = idx & 32767, s0 = j >> 3;
    int lane = threadIdx.x;
    const float* xr = x + (size_t)b * DDIM;
    const float* w1 = W1 + (size_t)j * DDIM;
    const float* w0 = W0 + (size_t)s0 * DDIM;
    double d1 = 0.0, d0 = 0.0;
    for (int k = lane; k < DDIM; k += 64) {
        double xv = (double)xr[k] - (double)b_dec[k];
        d1 += xv * (double)w1[k];
        d0 += xv * (double)w0[k];
    }
    for (int off = 32; off; off >>= 1) {
        d1 += __shfl_down(d1, off);
        d0 += __shfl_down(d0, off);
    }
    if (lane == 0) {
        double l1v = d1 + (double)b1[j];  l1v = l1v > 0.0 ? l1v : 0.0;
        double l0v = d0 + (double)b0[s0]; l0v = l0v > 0.0 ? l0v : 0.0;
        band_v[bi] = l1v * l0v;
    }
}

// exact in-band ranking: sort (v64 desc, idx asc), emit first k_rem
__global__ void k_final(unsigned* __restrict__ ctrl, const double* __restrict__ band_v,
                        uint2* __restrict__ extra) {
    __shared__ unsigned long long skey[BAND_CAP];
    __shared__ unsigned sidx[BAND_CAP];
    int t = threadIdx.x;
    unsigned n = umin_(ctrl[5], BAND_CAP);
    const unsigned* band_idx = ctrl + 6400;
    for (int i = t; i < BAND_CAP; i += 256) {
        if ((unsigned)i < n) {
            skey[i] = (unsigned long long)__double_as_longlong(band_v[i]); // v>=0: monotone bits
            sidx[i] = band_idx[i];
        } else {
            skey[i] = 0ull; sidx[i] = 0xFFFFFFFFu;
        }
    }
    __syncthreads();
    for (int kk = 2; kk <= BAND_CAP; kk <<= 1) {
        for (int jj = kk >> 1; jj > 0; jj >>= 1) {
            for (int i = t; i < BAND_CAP; i += 256) {
                int ixj = i ^ jj;
                if (ixj > i) {
                    unsigned long long ka = skey[i], kb = skey[ixj];
                    unsigned ia = sidx[i], ib = sidx[ixj];
                    bool ab = (ka > kb) || (ka == kb && ia < ib);   // a-before-b in desired order
                    bool asc = ((i & kk) == 0);
                    if (asc ? !ab : ab) {
                        skey[i] = kb; skey[ixj] = ka;
                        sidx[i] = ib; sidx[ixj] = ia;
                    }
                }
            }
            __syncthreads();
        }
    }
    unsigned c_hi = ctrl[4];
    unsigned k_rem = (c_hi < KTOT) ? (KTOT - c_hi) : 0u;
    if (k_rem > n) k_rem = n;
    if (t == 0) ctrl[6] = k_rem;
    for (unsigned i = t; i < k_rem; i += 256)
        extra[i] = make_uint2(sidx[i],
                              __float_as_uint((float)__longlong_as_double((long long)skey[i])));
}

// per-row CSR build: auto-selected (v > band_hi)
__global__ void k_rows_a(const uint2* __restrict__ cand, const unsigned* __restrict__ ctrl,
                         unsigned* __restrict__ rowc, uint2* __restrict__ rowd) {
    unsigned n = umin_(ctrl[0], CAND_CAP);
    unsigned H = ctrl[3];
    float hi = __uint_as_float((H + 1u) << 8) + DELTA;
    for (unsigned i = blockIdx.x * 256 + threadIdx.x; i < n; i += gridDim.x * 256) {
        unsigned u = cand[i].x;
        if (__uint_as_float(u) > hi) {
            unsigned idx = cand[i].y;
            unsigned b = idx >> 15;
            unsigned p = atomicAdd(&rowc[b], 1u);
            if (p < 256u) rowd[(b << 8) + p] = make_uint2(idx & 32767u, u);
        }
    }
}

// per-row CSR build: band-selected
__global__ void k_rows_b(const unsigned* __restrict__ ctrl, const uint2* __restrict__ extra,
                         unsigned* __restrict__ rowc, uint2* __restrict__ rowd) {
    unsigned k_rem = ctrl[6];
    for (unsigned i = blockIdx.x * 256 + threadIdx.x; i < k_rem; i += gridDim.x * 256) {
        unsigned idx = extra[i].x;
        unsigned b = idx >> 15;
        unsigned p = atomicAdd(&rowc[b], 1u);
        if (p < 256u) rowd[(b << 8) + p] = make_uint2(idx & 32767u, extra[i].y);
    }
}

// decode: out[b,:] = b_dec + sum v * WdT[j,:]
__launch_bounds__(256) __global__
void k_decode(const uint2* __restrict__ rowd, const unsigned* __restrict__ rowc,
              const float* __restrict__ WdT, const float* __restrict__ b_dec,
              float* __restrict__ out) {
    __shared__ uint2 e[256];
    int b = blockIdx.x, t = threadIdx.x;
    unsigned c = rowc[b]; if (c > 256u) c = 256u;
    if ((unsigned)t < c) e[t] = rowd[(b << 8) + t];
    __syncthreads();
    float a0 = b_dec[t], a1 = b_dec[t + 256], a2 = b_dec[t + 512];
#pragma unroll 4
    for (unsigned i = 0; i < c; ++i) {
        float v = __uint_as_float(e[i].y);
        const float* w = WdT + (size_t)e[i].x * DDIM;
        a0 = fmaf(v, w[t], a0);
        a1 = fmaf(v, w[t + 256], a1);
        a2 = fmaf(v, w[t + 512], a2);
    }
    float* o = out + (size_t)b * DDIM;
    o[t] = a0; o[t + 256] = a1; o[t + 512] = a2;
}

extern "C" void kernel_launch(void* const* d_in, const int* in_sizes, int n_in,
                              void* d_out, int out_size, void* d_ws, size_t ws_size,
                              hipStream_t stream) {
    const float* x     = (const float*)d_in[0];
    const float* W0    = (const float*)d_in[1];
    const float* b0    = (const float*)d_in[2];
    const float* W1    = (const float*)d_in[3];
    const float* b1    = (const float*)d_in[4];
    const float* Wd    = (const float*)d_in[5];
    const float* b_dec = (const float*)d_in[6];
    float* out = (float*)d_out;

    if (ws_size < WS_NEED) {   // insufficient workspace: fail cleanly (absmax == max|ref|)
        hipMemsetAsync(d_out, 0, (size_t)out_size * sizeof(float), stream);
        return;
    }

    char* ws = (char*)d_ws;
    float*    l0     = (float*)(ws + OFF_L0);
    float*    xc     = (float*)(ws + OFF_XC);
    float*    WdT    = (float*)(ws + OFF_WDT);
    unsigned* ctrl   = (unsigned*)(ws + OFF_CTRL);
    double*   band_v = (double*)(ws + OFF_CTRL + 65536);
    uint2*    extra  = (uint2*)(ws + OFF_CTRL + 98304);
    unsigned* rowc   = (unsigned*)(ws + OFF_ROWC);
    uint2*    rowd   = (uint2*)(ws + OFF_ROWD);
    uint2*    cand   = (uint2*)(ws + OFF_CAND);

    // zero control vars + hist1 + hist2 (6400 u32) and row counts
    hipMemsetAsync(ctrl, 0, 6400 * sizeof(unsigned), stream);
    hipMemsetAsync(rowc, 0, BROWS * sizeof(unsigned), stream);

    k_prep_xc<<<(BROWS * DDIM / 4) / 256, 256, 0, stream>>>(x, b_dec, xc);
    k_transpose<<<dim3(DICT / 32, DDIM / 32), 256, 0, stream>>>(Wd, WdT);

    k_gemm<0><<<dim3(S0N / 128, BROWS / 128), 256, 0, stream>>>(xc, W0, b0, l0, nullptr, nullptr);
    k_gemm<1><<<dim3(DICT / 128, BROWS / 128), 256, 0, stream>>>(xc, W1, b1, l0, cand, ctrl);

    k_hist1<<<1024, 256, 0, stream>>>(cand, ctrl);
    k_scan1<<<1, 256, 0, stream>>>(ctrl);
    k_hist2<<<1024, 256, 0, stream>>>(cand, ctrl);
    k_scan2<<<1, 256, 0, stream>>>(ctrl);
    k_band<<<1024, 256, 0, stream>>>(cand, ctrl);
    k_f64<<<BAND_CAP, 64, 0, stream>>>(x, b_dec, W0, b0, W1, b1, ctrl, band_v);
    k_final<<<1, 256, 0, stream>>>(ctrl, band_v, extra);

    k_rows_a<<<1024, 256, 0, stream>>>(cand, ctrl, rowc, rowd);
    k_rows_b<<<32, 256, 0, stream>>>(ctrl, extra, rowc, rowd);
    k_decode<<<BROWS, 256, 0, stream>>>(rowd, rowc, WdT, b_dec, out);
}

// Round 2
// 1351.583 us; speedup vs baseline: 2.3599x; 2.3599x over previous
//
#include <hip/hip_runtime.h>
#include <stdint.h>

#define DDIM 768
#define BROWS 4096
#define S0N 4096
#define DICT 32768
#define KTOT 262144u
#define PREF 2.0f
#define DELTA 4e-3f
#define CAND_CAP 8388608u
#define BAND_CAP 4096

// workspace layout (bytes)
static constexpr size_t OFF_XH   = 0;            // 4096*768*2  = 6 MiB
static constexpr size_t OFF_XL   = 6291456;
static constexpr size_t OFF_W0H  = 12582912;
static constexpr size_t OFF_W0L  = 18874368;
static constexpr size_t OFF_W1H  = 25165824;     // 32768*768*2 = 48 MiB
static constexpr size_t OFF_W1L  = 75497472;     // split region ends 125829120
static constexpr size_t OFF_WDT  = 0;            // aliases split region (dead after gemms)
static constexpr size_t OFF_L0   = 125829120;    // 64 MiB
static constexpr size_t OFF_CTRL = 192937984;    // 128 KiB
static constexpr size_t OFF_ROWC = 193069056;    // 16 KiB
static constexpr size_t OFF_ROWD = 193085440;    // 8 MiB
static constexpr size_t OFF_CAND = 201474048;    // 8M*8 = 64 MiB
static constexpr size_t WS_NEED  = 268582912;

// ctrl u32 layout: [0]=cand_cnt [1]=binT [2]=c1 [3]=H [4]=c_hi [5]=band_cnt [6]=k_rem
// hist1 @ ctrl+256 (2048), hist2 @ ctrl+2304 (4096), band_idx @ ctrl+6400 (4096)
// band_v64 (double[4096]) @ OFF_CTRL+65536 ; extra (uint2[4096]) @ OFF_CTRL+98304

typedef __attribute__((ext_vector_type(8))) short bf16x8;
typedef __attribute__((ext_vector_type(4))) float f32x4;

__device__ __forceinline__ unsigned umin_(unsigned a, unsigned b) { return a < b ? a : b; }
__device__ __forceinline__ float relu_(float v) { return v > 0.f ? v : 0.f; }

__device__ __forceinline__ unsigned short f2bf(float f) {
    union { float f; unsigned u; } v; v.f = f;
    unsigned r = v.u + 0x7FFFu + ((v.u >> 16) & 1u);
    return (unsigned short)(r >> 16);
}
__device__ __forceinline__ float bf2f(unsigned short h) {
    union { float f; unsigned u; } v; v.u = ((unsigned)h) << 16;
    return v.f;
}
__device__ __forceinline__ void split1(float a, short& h, short& l) {
    unsigned short hb = f2bf(a);
    float rem = a - bf2f(hb);
    h = (short)hb;
    l = (short)f2bf(rem);
}

__device__ __forceinline__ void gl16(const void* g, void* l) {
    __builtin_amdgcn_global_load_lds(
        (const __attribute__((address_space(1))) void*)g,
        (__attribute__((address_space(3))) void*)l,
        16, 0, 0);
}

// ---------------- split xc = x - b_dec into bf16 hi/lo ----------------
__global__ void k_split_x(const float* __restrict__ x, const float* __restrict__ b_dec,
                          short* __restrict__ XH, short* __restrict__ XL) {
    int i = blockIdx.x * 256 + threadIdx.x;           // float4 index, exact grid
    float4 xv = ((const float4*)x)[i];
    int d = (i % (DDIM / 4)) * 4;
    float4 bv = *(const float4*)(b_dec + d);
    float a[4] = {xv.x - bv.x, xv.y - bv.y, xv.z - bv.z, xv.w - bv.w};
    short4 h, lo;
    split1(a[0], h.x, lo.x); split1(a[1], h.y, lo.y);
    split1(a[2], h.z, lo.z); split1(a[3], h.w, lo.w);
    ((short4*)XH)[i] = h;
    ((short4*)XL)[i] = lo;
}

// ---------------- split W into bf16 hi/lo ----------------
__global__ void k_split_w(const float* __restrict__ W, short* __restrict__ H,
                          short* __restrict__ L) {
    int i = blockIdx.x * 256 + threadIdx.x;
    float4 wv = ((const float4*)W)[i];
    short4 h, lo;
    split1(wv.x, h.x, lo.x); split1(wv.y, h.y, lo.y);
    split1(wv.z, h.z, lo.z); split1(wv.w, h.w, lo.w);
    ((short4*)H)[i] = h;
    ((short4*)L)[i] = lo;
}

// ---------------- WdT[j][d] = Wd[d][j] ----------------
__global__ void k_transpose(const float* __restrict__ Wd, float* __restrict__ WdT) {
    __shared__ float tile[32][33];
    int j0 = blockIdx.x * 32, d0 = blockIdx.y * 32;
    int tx = threadIdx.x & 31, ty = threadIdx.x >> 5;   // 32 x 8
#pragma unroll
    for (int i = 0; i < 4; ++i)
        tile[ty + i * 8][tx] = Wd[(size_t)(d0 + ty + i * 8) * DICT + j0 + tx];
    __syncthreads();
#pragma unroll
    for (int i = 0; i < 4; ++i)
        WdT[(size_t)(j0 + ty + i * 8) * DDIM + d0 + tx] = tile[tx][ty + i * 8];
}

// ---------------- split-bf16 MFMA GEMM: C = relu(A @ W^T + bias) [, gate & append] ----
// A=[4096,768] via (XH+XL), W=[N,768] via (WH+WL); acc = AH*BH + AH*BL + AL*BH.
// 128x128 tile, BK=32, 256 thr = 4 waves (2x2), per wave 4x4 frags of 16x16x32.
template<int EPI>
__launch_bounds__(256, 2) __global__
void k_mm(const short* __restrict__ XH, const short* __restrict__ XL,
          const short* __restrict__ WH, const short* __restrict__ WL,
          const float* __restrict__ bias, float* __restrict__ l0buf,
          uint2* __restrict__ cand, unsigned* __restrict__ ctrl) {
    __shared__ short sAH[4096], sAL[4096], sBH[4096], sBL[4096];
    __shared__ unsigned pscan[256];
    __shared__ unsigned basev;

    const int t = threadIdx.x;
    const int w = t >> 6, l = t & 63;
    const int wm = w >> 1, wn = w & 1;
    const int bm = blockIdx.y << 7, bn = blockIdx.x << 7;

    // staging: chunk c = t covers row c>>2 (0..63), chunk c = t+256 covers row+64
    const size_t aoff = (size_t)(bm + (t >> 2)) * DDIM + ((t & 3) << 3);
    const size_t boff = (size_t)(bn + (t >> 2)) * DDIM + ((t & 3) << 3);
    const size_t rstep = (size_t)64 * DDIM;
    short* dA0h = &sAH[t * 8]; short* dA1h = &sAH[t * 8 + 2048];
    short* dA0l = &sAL[t * 8]; short* dA1l = &sAL[t * 8 + 2048];
    short* dB0h = &sBH[t * 8]; short* dB1h = &sBH[t * 8 + 2048];
    short* dB0l = &sBL[t * 8]; short* dB1l = &sBL[t * 8 + 2048];

    f32x4 acc[4][4];
#pragma unroll
    for (int i = 0; i < 4; ++i)
#pragma unroll
        for (int j = 0; j < 4; ++j) acc[i][j] = (f32x4){0.f, 0.f, 0.f, 0.f};

    // fragment addressing: lane l holds (row = frow, k = fkg*8 .. +7)
    const int frow = l & 15, fkg = l >> 4;
    const int abase = (wm * 64 + frow) * 32 + fkg * 8;
    const int bbase = (wn * 64 + frow) * 32 + fkg * 8;

    for (int kt = 0; kt < DDIM / 32; ++kt) {
        __syncthreads();
        const size_t ks = (size_t)kt * 32;
        gl16(XH + aoff + ks, dA0h); gl16(XH + aoff + rstep + ks, dA1h);
        gl16(XL + aoff + ks, dA0l); gl16(XL + aoff + rstep + ks, dA1l);
        gl16(WH + boff + ks, dB0h); gl16(WH + boff + rstep + ks, dB1h);
        gl16(WL + boff + ks, dB0l); gl16(WL + boff + rstep + ks, dB1l);
        __syncthreads();

        bf16x8 ah[4], al[4], bh[4], bl[4];
#pragma unroll
        for (int i = 0; i < 4; ++i) {
            ah[i] = *(const bf16x8*)&sAH[abase + i * 512];
            al[i] = *(const bf16x8*)&sAL[abase + i * 512];
            bh[i] = *(const bf16x8*)&sBH[bbase + i * 512];
            bl[i] = *(const bf16x8*)&sBL[bbase + i * 512];
        }
#pragma unroll
        for (int i = 0; i < 4; ++i)
#pragma unroll
            for (int j = 0; j < 4; ++j)
                acc[i][j] = __builtin_amdgcn_mfma_f32_16x16x32_bf16(ah[i], bh[j], acc[i][j], 0, 0, 0);
#pragma unroll
        for (int i = 0; i < 4; ++i)
#pragma unroll
            for (int j = 0; j < 4; ++j)
                acc[i][j] = __builtin_amdgcn_mfma_f32_16x16x32_bf16(ah[i], bl[j], acc[i][j], 0, 0, 0);
#pragma unroll
        for (int i = 0; i < 4; ++i)
#pragma unroll
            for (int j = 0; j < 4; ++j)
                acc[i][j] = __builtin_amdgcn_mfma_f32_16x16x32_bf16(al[i], bh[j], acc[i][j], 0, 0, 0);
    }

    // C/D layout (m89-verified): col = lane&15, row = (lane>>4)*4 + reg
    if constexpr (EPI == 0) {
#pragma unroll
        for (int i = 0; i < 4; ++i) {
#pragma unroll
            for (int r = 0; r < 4; ++r) {
                int row = bm + wm * 64 + i * 16 + fkg * 4 + r;
                float* orow = l0buf + (size_t)row * S0N;
#pragma unroll
                for (int j = 0; j < 4; ++j) {
                    int col = bn + wn * 64 + j * 16 + frow;
                    orow[col] = relu_(acc[i][j][r] + bias[col]);
                }
            }
        }
    } else {
        unsigned cnt = 0;
#pragma unroll
        for (int i = 0; i < 4; ++i)
#pragma unroll
            for (int j = 0; j < 4; ++j)
#pragma unroll
                for (int r = 0; r < 4; ++r) {
                    int row = bm + wm * 64 + i * 16 + fkg * 4 + r;
                    int col = bn + wn * 64 + j * 16 + frow;
                    float v = relu_(acc[i][j][r] + bias[col]);
                    v *= l0buf[(size_t)row * S0N + (col >> 3)];
                    acc[i][j][r] = v;
                    cnt += (v >= PREF) ? 1u : 0u;
                }
        pscan[t] = cnt;
        __syncthreads();
        for (int s = 1; s < 256; s <<= 1) {
            unsigned v2 = (t >= s) ? pscan[t - s] : 0u;
            __syncthreads();
            pscan[t] += v2;
            __syncthreads();
        }
        if (t == 255) basev = atomicAdd(&ctrl[0], pscan[255]);
        __syncthreads();
        unsigned off = basev + pscan[t] - cnt;
#pragma unroll
        for (int i = 0; i < 4; ++i)
#pragma unroll
            for (int j = 0; j < 4; ++j)
#pragma unroll
                for (int r = 0; r < 4; ++r) {
                    float v = acc[i][j][r];
                    if (v >= PREF) {
                        int row = bm + wm * 64 + i * 16 + fkg * 4 + r;
                        int col = bn + wn * 64 + j * 16 + frow;
                        if (off < CAND_CAP)
                            cand[off] = make_uint2(__float_as_uint(v),
                                                   ((unsigned)row << 15) | (unsigned)col);
                        ++off;
                    }
                }
    }
}

// ---------------- selection: histograms over candidate float bits ----------------
__global__ void k_hist1(const uint2* __restrict__ cand, unsigned* __restrict__ ctrl) {
    __shared__ unsigned h[2048];
    for (int i = threadIdx.x; i < 2048; i += 256) h[i] = 0;
    __syncthreads();
    unsigned n = umin_(ctrl[0], CAND_CAP);
    for (unsigned i = blockIdx.x * 256 + threadIdx.x; i < n; i += gridDim.x * 256)
        atomicAdd(&h[cand[i].x >> 20], 1u);
    __syncthreads();
    unsigned* hist = ctrl + 256;
    for (int i = threadIdx.x; i < 2048; i += 256)
        if (h[i]) atomicAdd(&hist[i], h[i]);
}

__global__ void k_scan1(unsigned* __restrict__ ctrl) {
    __shared__ unsigned hs[2048];
    __shared__ unsigned cs[256];
    const unsigned* h = ctrl + 256;
    int t = threadIdx.x;
    for (int i = t; i < 2048; i += 256) hs[i] = h[i];
    __syncthreads();
    unsigned s = 0;
    for (int b = 0; b < 8; ++b) s += hs[t * 8 + b];
    cs[t] = s;
    __syncthreads();
    if (t == 0) {
        unsigned cum = 0, T = 0, cb = 0;
        for (int c = 255; c >= 0; --c) {
            if (cum + cs[c] >= KTOT) {
                for (int b = c * 8 + 7; b >= c * 8; --b) {
                    cum += hs[b];
                    if (cum >= KTOT) { T = (unsigned)b; cb = cum - hs[b]; break; }
                }
                break;
            }
            cum += cs[c];
        }
        ctrl[1] = T; ctrl[2] = cb;
    }
}

__global__ void k_hist2(const uint2* __restrict__ cand, unsigned* __restrict__ ctrl) {
    unsigned n = umin_(ctrl[0], CAND_CAP);
    unsigned T = ctrl[1];
    unsigned* hist2 = ctrl + 2304;
    for (unsigned i = blockIdx.x * 256 + threadIdx.x; i < n; i += gridDim.x * 256) {
        unsigned u = cand[i].x;
        if ((u >> 20) == T) atomicAdd(&hist2[(u >> 8) & 0xFFFu], 1u);
    }
}

__global__ void k_scan2(unsigned* __restrict__ ctrl) {
    __shared__ unsigned hs[4096];
    __shared__ unsigned cs[256];
    const unsigned* h = ctrl + 2304;
    int t = threadIdx.x;
    for (int i = t; i < 4096; i += 256) hs[i] = h[i];
    __syncthreads();
    unsigned s = 0;
    for (int b = 0; b < 16; ++b) s += hs[t * 16 + b];
    cs[t] = s;
    __syncthreads();
    if (t == 0) {
        unsigned cum = ctrl[2], T2 = 0;
        for (int c = 255; c >= 0; --c) {
            if (cum + cs[c] >= KTOT) {
                for (int b = c * 16 + 15; b >= c * 16; --b) {
                    cum += hs[b];
                    if (cum >= KTOT) { T2 = (unsigned)b; break; }
                }
                break;
            }
            cum += cs[c];
        }
        ctrl[3] = (ctrl[1] << 12) | T2;   // 24-bit prefix H
    }
}

// count strictly-above band, collect band members
__global__ void k_band(const uint2* __restrict__ cand, unsigned* __restrict__ ctrl) {
    __shared__ unsigned lhi;
    if (threadIdx.x == 0) lhi = 0;
    __syncthreads();
    unsigned n = umin_(ctrl[0], CAND_CAP);
    unsigned H = ctrl[3];
    float lo = __uint_as_float(H << 8) - DELTA;
    float hi = __uint_as_float((H + 1u) << 8) + DELTA;
    unsigned* band_idx = ctrl + 6400;
    unsigned my = 0;
    for (unsigned i = blockIdx.x * 256 + threadIdx.x; i < n; i += gridDim.x * 256) {
        float v = __uint_as_float(cand[i].x);
        if (v > hi) ++my;
        else if (v >= lo) {
            unsigned p = atomicAdd(&ctrl[5], 1u);
            if (p < BAND_CAP) band_idx[p] = cand[i].y;
        }
    }
    atomicAdd(&lhi, my);
    __syncthreads();
    if (threadIdx.x == 0 && lhi) atomicAdd(&ctrl[4], lhi);
}

// f64 recompute of band elements (exact-vs-numpy selection values)
__global__ void k_f64(const float* __restrict__ x, const float* __restrict__ b_dec,
                      const float* __restrict__ W0, const float* __restrict__ b0,
                      const float* __restrict__ W1, const float* __restrict__ b1,
                      const unsigned* __restrict__ ctrl, double* __restrict__ band_v) {
    unsigned n = umin_(ctrl[5], BAND_CAP);
    unsigned bi = blockIdx.x;
    if (bi >= n) return;
    const unsigned* band_idx = ctrl + 6400;
    unsigned idx = band_idx[bi];
    int b = idx >> 15, j = idx & 32767, s0 = j >> 3;
    int lane = threadIdx.x;
    const float* xr = x + (size_t)b * DDIM;
    const float* w1 = W1 + (size_t)j * DDIM;
    const float* w0 = W0 + (size_t)s0 * DDIM;
    double d1 = 0.0, d0 = 0.0;
    for (int k = lane; k < DDIM; k += 64) {
        double xv = (double)xr[k] - (double)b_dec[k];
        d1 += xv * (double)w1[k];
        d0 += xv * (double)w0[k];
    }
    for (int off = 32; off; off >>= 1) {
        d1 += __shfl_down(d1, off);
        d0 += __shfl_down(d0, off);
    }
    if (lane == 0) {
        double l1v = d1 + (double)b1[j];  l1v = l1v > 0.0 ? l1v : 0.0;
        double l0v = d0 + (double)b0[s0]; l0v = l0v > 0.0 ? l0v : 0.0;
        band_v[bi] = l1v * l0v;
    }
}

// exact in-band ranking: sort (v64 desc, idx asc), emit first k_rem
__global__ void k_final(unsigned* __restrict__ ctrl, const double* __restrict__ band_v,
                        uint2* __restrict__ extra) {
    __shared__ unsigned long long skey[BAND_CAP];
    __shared__ unsigned sidx[BAND_CAP];
    int t = threadIdx.x;
    unsigned n = umin_(ctrl[5], BAND_CAP);
    const unsigned* band_idx = ctrl + 6400;
    for (int i = t; i < BAND_CAP; i += 256) {
        if ((unsigned)i < n) {
            skey[i] = (unsigned long long)__double_as_longlong(band_v[i]); // v>=0: monotone bits
            sidx[i] = band_idx[i];
        } else {
            skey[i] = 0ull; sidx[i] = 0xFFFFFFFFu;
        }
    }
    __syncthreads();
    for (int kk = 2; kk <= BAND_CAP; kk <<= 1) {
        for (int jj = kk >> 1; jj > 0; jj >>= 1) {
            for (int i = t; i < BAND_CAP; i += 256) {
                int ixj = i ^ jj;
                if (ixj > i) {
                    unsigned long long ka = skey[i], kb = skey[ixj];
                    unsigned ia = sidx[i], ib = sidx[ixj];
                    bool ab = (ka > kb) || (ka == kb && ia < ib);
                    bool asc = ((i & kk) == 0);
                    if (asc ? !ab : ab) {
                        skey[i] = kb; skey[ixj] = ka;
                        sidx[i] = ib; sidx[ixj] = ia;
                    }
                }
            }
            __syncthreads();
        }
    }
    unsigned c_hi = ctrl[4];
    unsigned k_rem = (c_hi < KTOT) ? (KTOT - c_hi) : 0u;
    if (k_rem > n) k_rem = n;
    if (t == 0) ctrl[6] = k_rem;
    for (unsigned i = t; i < k_rem; i += 256)
        extra[i] = make_uint2(sidx[i],
                              __float_as_uint((float)__longlong_as_double((long long)skey[i])));
}

// per-row CSR build: auto-selected (v > band_hi)
__global__ void k_rows_a(const uint2* __restrict__ cand, const unsigned* __restrict__ ctrl,
                         unsigned* __restrict__ rowc, uint2* __restrict__ rowd) {
    unsigned n = umin_(ctrl[0], CAND_CAP);
    unsigned H = ctrl[3];
    float hi = __uint_as_float((H + 1u) << 8) + DELTA;
    for (unsigned i = blockIdx.x * 256 + threadIdx.x; i < n; i += gridDim.x * 256) {
        unsigned u = cand[i].x;
        if (__uint_as_float(u) > hi) {
            unsigned idx = cand[i].y;
            unsigned b = idx >> 15;
            unsigned p = atomicAdd(&rowc[b], 1u);
            if (p < 256u) rowd[(b << 8) + p] = make_uint2(idx & 32767u, u);
        }
    }
}

// per-row CSR build: band-selected
__global__ void k_rows_b(const unsigned* __restrict__ ctrl, const uint2* __restrict__ extra,
                         unsigned* __restrict__ rowc, uint2* __restrict__ rowd) {
    unsigned k_rem = ctrl[6];
    for (unsigned i = blockIdx.x * 256 + threadIdx.x; i < k_rem; i += gridDim.x * 256) {
        unsigned idx = extra[i].x;
        unsigned b = idx >> 15;
        unsigned p = atomicAdd(&rowc[b], 1u);
        if (p < 256u) rowd[(b << 8) + p] = make_uint2(idx & 32767u, extra[i].y);
    }
}

// decode: out[b,:] = b_dec + sum v * WdT[j,:]
__launch_bounds__(256) __global__
void k_decode(const uint2* __restrict__ rowd, const unsigned* __restrict__ rowc,
              const float* __restrict__ WdT, const float* __restrict__ b_dec,
              float* __restrict__ out) {
    __shared__ uint2 e[256];
    int b = blockIdx.x, t = threadIdx.x;
    unsigned c = rowc[b]; if (c > 256u) c = 256u;
    if ((unsigned)t < c) e[t] = rowd[(b << 8) + t];
    __syncthreads();
    float a0 = b_dec[t], a1 = b_dec[t + 256], a2 = b_dec[t + 512];
#pragma unroll 4
    for (unsigned i = 0; i < c; ++i) {
        float v = __uint_as_float(e[i].y);
        const float* w = WdT + (size_t)e[i].x * DDIM;
        a0 = fmaf(v, w[t], a0);
        a1 = fmaf(v, w[t + 256], a1);
        a2 = fmaf(v, w[t + 512], a2);
    }
    float* o = out + (size_t)b * DDIM;
    o[t] = a0; o[t + 256] = a1; o[t + 512] = a2;
}

extern "C" void kernel_launch(void* const* d_in, const int* in_sizes, int n_in,
                              void* d_out, int out_size, void* d_ws, size_t ws_size,
                              hipStream_t stream) {
    const float* x     = (const float*)d_in[0];
    const float* W0    = (const float*)d_in[1];
    const float* b0    = (const float*)d_in[2];
    const float* W1    = (const float*)d_in[3];
    const float* b1    = (const float*)d_in[4];
    const float* Wd    = (const float*)d_in[5];
    const float* b_dec = (const float*)d_in[6];
    float* out = (float*)d_out;

    if (ws_size < WS_NEED) {   // insufficient workspace: fail cleanly
        hipMemsetAsync(d_out, 0, (size_t)out_size * sizeof(float), stream);
        return;
    }

    char* ws = (char*)d_ws;
    short*    XH     = (short*)(ws + OFF_XH);
    short*    XL     = (short*)(ws + OFF_XL);
    short*    W0H    = (short*)(ws + OFF_W0H);
    short*    W0L    = (short*)(ws + OFF_W0L);
    short*    W1H    = (short*)(ws + OFF_W1H);
    short*    W1L    = (short*)(ws + OFF_W1L);
    float*    WdT    = (float*)(ws + OFF_WDT);     // aliases split region
    float*    l0     = (float*)(ws + OFF_L0);
    unsigned* ctrl   = (unsigned*)(ws + OFF_CTRL);
    double*   band_v = (double*)(ws + OFF_CTRL + 65536);
    uint2*    extra  = (uint2*)(ws + OFF_CTRL + 98304);
    unsigned* rowc   = (unsigned*)(ws + OFF_ROWC);
    uint2*    rowd   = (uint2*)(ws + OFF_ROWD);
    uint2*    cand   = (uint2*)(ws + OFF_CAND);

    hipMemsetAsync(ctrl, 0, 6400 * sizeof(unsigned), stream);
    hipMemsetAsync(rowc, 0, BROWS * sizeof(unsigned), stream);

    k_split_x<<<(BROWS * DDIM / 4) / 256, 256, 0, stream>>>(x, b_dec, XH, XL);
    k_split_w<<<(S0N * DDIM / 4) / 256, 256, 0, stream>>>(W0, W0H, W0L);
    k_split_w<<<(DICT * DDIM / 4) / 256, 256, 0, stream>>>(W1, W1H, W1L);

    k_mm<0><<<dim3(S0N / 128, BROWS / 128), 256, 0, stream>>>(XH, XL, W0H, W0L, b0, l0, nullptr, nullptr);
    k_mm<1><<<dim3(DICT / 128, BROWS / 128), 256, 0, stream>>>(XH, XL, W1H, W1L, b1, l0, cand, ctrl);

    // split region is dead now; WdT aliases it
    k_transpose<<<dim3(DICT / 32, DDIM / 32), 256, 0, stream>>>(Wd, WdT);

    k_hist1<<<1024, 256, 0, stream>>>(cand, ctrl);
    k_scan1<<<1, 256, 0, stream>>>(ctrl);
    k_hist2<<<1024, 256, 0, stream>>>(cand, ctrl);
    k_scan2<<<1, 256, 0, stream>>>(ctrl);
    k_band<<<1024, 256, 0, stream>>>(cand, ctrl);
    k_f64<<<BAND_CAP, 64, 0, stream>>>(x, b_dec, W0, b0, W1, b1, ctrl, band_v);
    k_final<<<1, 256, 0, stream>>>(ctrl, band_v, extra);

    k_rows_a<<<1024, 256, 0, stream>>>(cand, ctrl, rowc, rowd);
    k_rows_b<<<32, 256, 0, stream>>>(ctrl, extra, rowc, rowd);
    k_decode<<<BROWS, 256, 0, stream>>>(rowd, rowc, WdT, b_dec, out);
}

// Round 3
// 1309.931 us; speedup vs baseline: 2.4349x; 1.0318x over previous
//
#include <hip/hip_runtime.h>
#include <stdint.h>

#define DDIM 768
#define BROWS 4096
#define S0N 4096
#define DICT 32768
#define KTOT 262144u
#define PREF 2.0f
#define DELTA 4e-3f
#define CAND_CAP 8388608u
#define BAND_CAP 4096

// workspace layout (bytes)
static constexpr size_t OFF_XH   = 0;            // 4096*768*2  = 6 MiB
static constexpr size_t OFF_XL   = 6291456;
static constexpr size_t OFF_W0H  = 12582912;
static constexpr size_t OFF_W0L  = 18874368;
static constexpr size_t OFF_W1H  = 25165824;     // 32768*768*2 = 48 MiB
static constexpr size_t OFF_W1L  = 75497472;     // split region ends 125829120
static constexpr size_t OFF_WDT  = 0;            // aliases split region (dead after gemms)
static constexpr size_t OFF_L0   = 125829120;    // 64 MiB
static constexpr size_t OFF_CTRL = 192937984;    // 128 KiB
static constexpr size_t OFF_ROWC = 193069056;    // 16 KiB
static constexpr size_t OFF_ROWD = 193085440;    // 8 MiB
static constexpr size_t OFF_CAND = 201474048;    // 8M*8 = 64 MiB
static constexpr size_t WS_NEED  = 268582912;

// ctrl u32 layout: [0]=cand_cnt [1]=binT [2]=c1 [3]=H [4]=c_hi [5]=band_cnt [6]=k_rem
// hist1 @ ctrl+256 (2048), hist2 @ ctrl+2304 (4096), band_idx @ ctrl+6400 (4096)
// band_v64 (double[4096]) @ OFF_CTRL+65536 ; extra (uint2[4096]) @ OFF_CTRL+98304

typedef __attribute__((ext_vector_type(8))) short bf16x8;
typedef __attribute__((ext_vector_type(4))) float f32x4;

__device__ __forceinline__ unsigned umin_(unsigned a, unsigned b) { return a < b ? a : b; }
__device__ __forceinline__ float relu_(float v) { return v > 0.f ? v : 0.f; }

__device__ __forceinline__ unsigned short f2bf(float f) {
    union { float f; unsigned u; } v; v.f = f;
    unsigned r = v.u + 0x7FFFu + ((v.u >> 16) & 1u);
    return (unsigned short)(r >> 16);
}
__device__ __forceinline__ float bf2f(unsigned short h) {
    union { float f; unsigned u; } v; v.u = ((unsigned)h) << 16;
    return v.f;
}
__device__ __forceinline__ void split1(float a, short& h, short& l) {
    unsigned short hb = f2bf(a);
    float rem = a - bf2f(hb);
    h = (short)hb;
    l = (short)f2bf(rem);
}

__device__ __forceinline__ void gl16(const void* g, void* l) {
    __builtin_amdgcn_global_load_lds(
        (const __attribute__((address_space(1))) void*)g,
        (__attribute__((address_space(3))) void*)l,
        16, 0, 0);
}

// ---------------- split xc = x - b_dec into bf16 hi/lo ----------------
__global__ void k_split_x(const float* __restrict__ x, const float* __restrict__ b_dec,
                          short* __restrict__ XH, short* __restrict__ XL) {
    int i = blockIdx.x * 256 + threadIdx.x;           // float4 index, exact grid
    float4 xv = ((const float4*)x)[i];
    int d = (i % (DDIM / 4)) * 4;
    float4 bv = *(const float4*)(b_dec + d);
    float a[4] = {xv.x - bv.x, xv.y - bv.y, xv.z - bv.z, xv.w - bv.w};
    short4 h, lo;
    split1(a[0], h.x, lo.x); split1(a[1], h.y, lo.y);
    split1(a[2], h.z, lo.z); split1(a[3], h.w, lo.w);
    ((short4*)XH)[i] = h;
    ((short4*)XL)[i] = lo;
}

// ---------------- split W into bf16 hi/lo ----------------
__global__ void k_split_w(const float* __restrict__ W, short* __restrict__ H,
                          short* __restrict__ L) {
    int i = blockIdx.x * 256 + threadIdx.x;
    float4 wv = ((const float4*)W)[i];
    short4 h, lo;
    split1(wv.x, h.x, lo.x); split1(wv.y, h.y, lo.y);
    split1(wv.z, h.z, lo.z); split1(wv.w, h.w, lo.w);
    ((short4*)H)[i] = h;
    ((short4*)L)[i] = lo;
}

// ---------------- WdT[j][d] = Wd[d][j] ----------------
__global__ void k_transpose(const float* __restrict__ Wd, float* __restrict__ WdT) {
    __shared__ float tile[32][33];
    int j0 = blockIdx.x * 32, d0 = blockIdx.y * 32;
    int tx = threadIdx.x & 31, ty = threadIdx.x >> 5;   // 32 x 8
#pragma unroll
    for (int i = 0; i < 4; ++i)
        tile[ty + i * 8][tx] = Wd[(size_t)(d0 + ty + i * 8) * DICT + j0 + tx];
    __syncthreads();
#pragma unroll
    for (int i = 0; i < 4; ++i)
        WdT[(size_t)(j0 + ty + i * 8) * DDIM + d0 + tx] = tile[tx][ty + i * 8];
}

// ---------------- split-bf16 MFMA GEMM, 256x256 tile, 8-wave, 4-phase pipelined ----
// Virtual K = 2304: regions (XH,WH) (XH,WL) (XL,WH), BK=64, 36 K-tiles.
// LDS fragment-major: each MFMA frag block = 1KiB contiguous (lane l -> +l*16B),
// staged via gl_lds with pre-permuted per-lane GLOBAL source (linear LDS dest).
// A blocks (wm,mi,ks): id = wm*16+mi*2+ks (32 x 1KiB = 32KB); B (wn,nj,ks): wn*8+nj*2+ks.
template<int EPI>
__launch_bounds__(512, 2) __global__
void k_mm(const short* __restrict__ XH, const short* __restrict__ XL,
          const short* __restrict__ WH, const short* __restrict__ WL,
          const float* __restrict__ bias, float* __restrict__ l0buf,
          uint2* __restrict__ cand, unsigned* __restrict__ ctrl) {
    __shared__ __align__(16) char smem[131072];   // A: [2][32KB] @0, B: [2][32KB] @65536

    const int t = threadIdx.x;
    const int w = t >> 6, l = t & 63;
    const int wm = w >> 2, wn = w & 3;            // 2 x 4 wave grid
    const int lr = l & 15, lk = l >> 4;           // frag row / k-group

    const int nwg = gridDim.x;
    const int bid = blockIdx.x;
    const int swz = (bid & 7) * (nwg >> 3) + (bid >> 3);   // XCD-aware (nwg%8==0)
    const int bm = (swz & 15) << 8;
    const int bn = (swz >> 4) << 8;

    // per-lane global element offsets for this wave's 4 A + 4 B stage blocks
    unsigned idxA[4], idxB[4];
#pragma unroll
    for (int q = 0; q < 4; ++q) {
        const int ab = w * 4 + q;
        idxA[q] = (unsigned)(bm + (ab >> 4) * 128 + ((ab >> 1) & 7) * 16 + lr) * 768u
                + (unsigned)((ab & 1) * 32 + lk * 8);
        idxB[q] = (unsigned)(bn + (ab >> 3) * 64 + ((ab >> 1) & 3) * 16 + lr) * 768u
                + (unsigned)((ab & 1) * 32 + lk * 8);
    }

    f32x4 acc[8][4];
#pragma unroll
    for (int i = 0; i < 8; ++i)
#pragma unroll
        for (int j = 0; j < 4; ++j) acc[i][j] = (f32x4){0.f, 0.f, 0.f, 0.f};

    // prologue: stage K-tile 0 (region XH/WH, kbase 0) into buffer 0
#pragma unroll
    for (int q = 0; q < 4; ++q) {
        gl16(XH + idxA[q], smem + (w * 4 + q) * 1024);
        gl16(WH + idxB[q], smem + 65536 + (w * 4 + q) * 1024);
    }
    asm volatile("s_waitcnt vmcnt(0)" ::: "memory");
    __syncthreads();

    int cur = 0;
    for (int kt = 0; kt < 36; ++kt) {
        const int ktn = kt + 1;
        const bool hn = ktn < 36;
        const short* An; const short* Bn; unsigned kbn;
        if (ktn < 12)      { An = XH; Bn = WH; kbn = (unsigned)ktn * 64u; }
        else if (ktn < 24) { An = XH; Bn = WL; kbn = (unsigned)(ktn - 12) * 64u; }
        else               { An = XL; Bn = WH; kbn = (unsigned)(ktn - 24) * 64u; }
        char* stA = smem + (cur ^ 1) * 32768;
        char* stB = smem + 65536 + (cur ^ 1) * 32768;
        const short* rA = (const short*)(smem + cur * 32768);
        const short* rB = (const short*)(smem + 65536 + cur * 32768);

        bf16x8 bf[4];
#pragma unroll
        for (int p = 0; p < 4; ++p) {
            const int ks = p >> 1, mh = p & 1;
            bf16x8 af[4];
#pragma unroll
            for (int m2 = 0; m2 < 4; ++m2) {
                const int mi = mh * 4 + m2;
                af[m2] = *(const bf16x8*)(rA + ((wm * 16 + mi * 2 + ks) * 1024 + l * 16) / 2);
            }
            if (mh == 0) {
#pragma unroll
                for (int nj = 0; nj < 4; ++nj)
                    bf[nj] = *(const bf16x8*)(rB + ((wn * 8 + nj * 2 + ks) * 1024 + l * 16) / 2);
            }
            if (hn) {   // stage 1 A + 1 B chunk of next K-tile (spread over 4 phases)
                gl16(An + idxA[p] + kbn, stA + (w * 4 + p) * 1024);
                gl16(Bn + idxB[p] + kbn, stB + (w * 4 + p) * 1024);
            }
            __builtin_amdgcn_s_barrier();
            asm volatile("s_waitcnt lgkmcnt(0)" ::: "memory");
            __builtin_amdgcn_sched_barrier(0);
            __builtin_amdgcn_s_setprio(1);
#pragma unroll
            for (int m2 = 0; m2 < 4; ++m2)
#pragma unroll
                for (int nj = 0; nj < 4; ++nj)
                    acc[mh * 4 + m2][nj] = __builtin_amdgcn_mfma_f32_16x16x32_bf16(
                        af[m2], bf[nj], acc[mh * 4 + m2][nj], 0, 0, 0);
            __builtin_amdgcn_s_setprio(0);
            __builtin_amdgcn_s_barrier();
        }
        asm volatile("s_waitcnt vmcnt(0)" ::: "memory");   // next tile's stages landed
        __builtin_amdgcn_s_barrier();
        cur ^= 1;
    }
    __syncthreads();

    // C/D layout (m89-verified): col = lr, row = lk*4 + r
    if constexpr (EPI == 0) {
#pragma unroll
        for (int mi = 0; mi < 8; ++mi) {
#pragma unroll
            for (int r = 0; r < 4; ++r) {
                const int row = bm + wm * 128 + mi * 16 + lk * 4 + r;
                float* orow = l0buf + (size_t)row * S0N;
#pragma unroll
                for (int nj = 0; nj < 4; ++nj) {
                    const int col = bn + wn * 64 + nj * 16 + lr;
                    orow[col] = relu_(acc[mi][nj][r] + bias[col]);
                }
            }
        }
    } else {
        unsigned* pscan = (unsigned*)smem;     // reuse LDS (all tile reads done)
        unsigned cnt = 0;
#pragma unroll
        for (int mi = 0; mi < 8; ++mi)
#pragma unroll
            for (int nj = 0; nj < 4; ++nj)
#pragma unroll
                for (int r = 0; r < 4; ++r) {
                    const int row = bm + wm * 128 + mi * 16 + lk * 4 + r;
                    const int col = bn + wn * 64 + nj * 16 + lr;
                    float v = relu_(acc[mi][nj][r] + bias[col]);
                    v *= l0buf[(size_t)row * S0N + (col >> 3)];
                    acc[mi][nj][r] = v;
                    cnt += (v >= PREF) ? 1u : 0u;
                }
        pscan[t] = cnt;
        __syncthreads();
        for (int s = 1; s < 512; s <<= 1) {
            unsigned v2 = (t >= s) ? pscan[t - s] : 0u;
            __syncthreads();
            pscan[t] += v2;
            __syncthreads();
        }
        if (t == 511) pscan[512] = atomicAdd(&ctrl[0], pscan[511]);
        __syncthreads();
        unsigned off = pscan[512] + pscan[t] - cnt;
#pragma unroll
        for (int mi = 0; mi < 8; ++mi)
#pragma unroll
            for (int nj = 0; nj < 4; ++nj)
#pragma unroll
                for (int r = 0; r < 4; ++r) {
                    const float v = acc[mi][nj][r];
                    if (v >= PREF) {
                        const int row = bm + wm * 128 + mi * 16 + lk * 4 + r;
                        const int col = bn + wn * 64 + nj * 16 + lr;
                        if (off < CAND_CAP)
                            cand[off] = make_uint2(__float_as_uint(v),
                                                   ((unsigned)row << 15) | (unsigned)col);
                        ++off;
                    }
                }
    }
}

// ---------------- selection: histograms over candidate float bits ----------------
__global__ void k_hist1(const uint2* __restrict__ cand, unsigned* __restrict__ ctrl) {
    __shared__ unsigned h[2048];
    for (int i = threadIdx.x; i < 2048; i += 256) h[i] = 0;
    __syncthreads();
    unsigned n = umin_(ctrl[0], CAND_CAP);
    for (unsigned i = blockIdx.x * 256 + threadIdx.x; i < n; i += gridDim.x * 256)
        atomicAdd(&h[cand[i].x >> 20], 1u);
    __syncthreads();
    unsigned* hist = ctrl + 256;
    for (int i = threadIdx.x; i < 2048; i += 256)
        if (h[i]) atomicAdd(&hist[i], h[i]);
}

__global__ void k_scan1(unsigned* __restrict__ ctrl) {
    __shared__ unsigned hs[2048];
    __shared__ unsigned cs[256];
    const unsigned* h = ctrl + 256;
    int t = threadIdx.x;
    for (int i = t; i < 2048; i += 256) hs[i] = h[i];
    __syncthreads();
    unsigned s = 0;
    for (int b = 0; b < 8; ++b) s += hs[t * 8 + b];
    cs[t] = s;
    __syncthreads();
    if (t == 0) {
        unsigned cum = 0, T = 0, cb = 0;
        for (int c = 255; c >= 0; --c) {
            if (cum + cs[c] >= KTOT) {
                for (int b = c * 8 + 7; b >= c * 8; --b) {
                    cum += hs[b];
                    if (cum >= KTOT) { T = (unsigned)b; cb = cum - hs[b]; break; }
                }
                break;
            }
            cum += cs[c];
        }
        ctrl[1] = T; ctrl[2] = cb;
    }
}

__global__ void k_hist2(const uint2* __restrict__ cand, unsigned* __restrict__ ctrl) {
    unsigned n = umin_(ctrl[0], CAND_CAP);
    unsigned T = ctrl[1];
    unsigned* hist2 = ctrl + 2304;
    for (unsigned i = blockIdx.x * 256 + threadIdx.x; i < n; i += gridDim.x * 256) {
        unsigned u = cand[i].x;
        if ((u >> 20) == T) atomicAdd(&hist2[(u >> 8) & 0xFFFu], 1u);
    }
}

__global__ void k_scan2(unsigned* __restrict__ ctrl) {
    __shared__ unsigned hs[4096];
    __shared__ unsigned cs[256];
    const unsigned* h = ctrl + 2304;
    int t = threadIdx.x;
    for (int i = t; i < 4096; i += 256) hs[i] = h[i];
    __syncthreads();
    unsigned s = 0;
    for (int b = 0; b < 16; ++b) s += hs[t * 16 + b];
    cs[t] = s;
    __syncthreads();
    if (t == 0) {
        unsigned cum = ctrl[2], T2 = 0;
        for (int c = 255; c >= 0; --c) {
            if (cum + cs[c] >= KTOT) {
                for (int b = c * 16 + 15; b >= c * 16; --b) {
                    cum += hs[b];
                    if (cum >= KTOT) { T2 = (unsigned)b; break; }
                }
                break;
            }
            cum += cs[c];
        }
        ctrl[3] = (ctrl[1] << 12) | T2;   // 24-bit prefix H
    }
}

// count strictly-above band, collect band members
__global__ void k_band(const uint2* __restrict__ cand, unsigned* __restrict__ ctrl) {
    __shared__ unsigned lhi;
    if (threadIdx.x == 0) lhi = 0;
    __syncthreads();
    unsigned n = umin_(ctrl[0], CAND_CAP);
    unsigned H = ctrl[3];
    float lo = __uint_as_float(H << 8) - DELTA;
    float hi = __uint_as_float((H + 1u) << 8) + DELTA;
    unsigned* band_idx = ctrl + 6400;
    unsigned my = 0;
    for (unsigned i = blockIdx.x * 256 + threadIdx.x; i < n; i += gridDim.x * 256) {
        float v = __uint_as_float(cand[i].x);
        if (v > hi) ++my;
        else if (v >= lo) {
            unsigned p = atomicAdd(&ctrl[5], 1u);
            if (p < BAND_CAP) band_idx[p] = cand[i].y;
        }
    }
    atomicAdd(&lhi, my);
    __syncthreads();
    if (threadIdx.x == 0 && lhi) atomicAdd(&ctrl[4], lhi);
}

// f64 recompute of band elements (exact-vs-numpy selection values)
__global__ void k_f64(const float* __restrict__ x, const float* __restrict__ b_dec,
                      const float* __restrict__ W0, const float* __restrict__ b0,
                      const float* __restrict__ W1, const float* __restrict__ b1,
                      const unsigned* __restrict__ ctrl, double* __restrict__ band_v) {
    unsigned n = umin_(ctrl[5], BAND_CAP);
    unsigned bi = blockIdx.x;
    if (bi >= n) return;
    const unsigned* band_idx = ctrl + 6400;
    unsigned idx = band_idx[bi];
    int b = idx >> 15, j = idx & 32767, s0 = j >> 3;
    int lane = threadIdx.x;
    const float* xr = x + (size_t)b * DDIM;
    const float* w1 = W1 + (size_t)j * DDIM;
    const float* w0 = W0 + (size_t)s0 * DDIM;
    double d1 = 0.0, d0 = 0.0;
    for (int k = lane; k < DDIM; k += 64) {
        double xv = (double)xr[k] - (double)b_dec[k];
        d1 += xv * (double)w1[k];
        d0 += xv * (double)w0[k];
    }
    for (int off = 32; off; off >>= 1) {
        d1 += __shfl_down(d1, off);
        d0 += __shfl_down(d0, off);
    }
    if (lane == 0) {
        double l1v = d1 + (double)b1[j];  l1v = l1v > 0.0 ? l1v : 0.0;
        double l0v = d0 + (double)b0[s0]; l0v = l0v > 0.0 ? l0v : 0.0;
        band_v[bi] = l1v * l0v;
    }
}

// exact in-band ranking: sort (v64 desc, idx asc), emit first k_rem
__global__ void k_final(unsigned* __restrict__ ctrl, const double* __restrict__ band_v,
                        uint2* __restrict__ extra) {
    __shared__ unsigned long long skey[BAND_CAP];
    __shared__ unsigned sidx[BAND_CAP];
    int t = threadIdx.x;
    unsigned n = umin_(ctrl[5], BAND_CAP);
    const unsigned* band_idx = ctrl + 6400;
    for (int i = t; i < BAND_CAP; i += 256) {
        if ((unsigned)i < n) {
            skey[i] = (unsigned long long)__double_as_longlong(band_v[i]); // v>=0: monotone bits
            sidx[i] = band_idx[i];
        } else {
            skey[i] = 0ull; sidx[i] = 0xFFFFFFFFu;
        }
    }
    __syncthreads();
    for (int kk = 2; kk <= BAND_CAP; kk <<= 1) {
        for (int jj = kk >> 1; jj > 0; jj >>= 1) {
            for (int i = t; i < BAND_CAP; i += 256) {
                int ixj = i ^ jj;
                if (ixj > i) {
                    unsigned long long ka = skey[i], kb = skey[ixj];
                    unsigned ia = sidx[i], ib = sidx[ixj];
                    bool ab = (ka > kb) || (ka == kb && ia < ib);
                    bool asc = ((i & kk) == 0);
                    if (asc ? !ab : ab) {
                        skey[i] = kb; skey[ixj] = ka;
                        sidx[i] = ib; sidx[ixj] = ia;
                    }
                }
            }
            __syncthreads();
        }
    }
    unsigned c_hi = ctrl[4];
    unsigned k_rem = (c_hi < KTOT) ? (KTOT - c_hi) : 0u;
    if (k_rem > n) k_rem = n;
    if (t == 0) ctrl[6] = k_rem;
    for (unsigned i = t; i < k_rem; i += 256)
        extra[i] = make_uint2(sidx[i],
                              __float_as_uint((float)__longlong_as_double((long long)skey[i])));
}

// per-row CSR build: auto-selected (v > band_hi)
__global__ void k_rows_a(const uint2* __restrict__ cand, const unsigned* __restrict__ ctrl,
                         unsigned* __restrict__ rowc, uint2* __restrict__ rowd) {
    unsigned n = umin_(ctrl[0], CAND_CAP);
    unsigned H = ctrl[3];
    float hi = __uint_as_float((H + 1u) << 8) + DELTA;
    for (unsigned i = blockIdx.x * 256 + threadIdx.x; i < n; i += gridDim.x * 256) {
        unsigned u = cand[i].x;
        if (__uint_as_float(u) > hi) {
            unsigned idx = cand[i].y;
            unsigned b = idx >> 15;
            unsigned p = atomicAdd(&rowc[b], 1u);
            if (p < 256u) rowd[(b << 8) + p] = make_uint2(idx & 32767u, u);
        }
    }
}

// per-row CSR build: band-selected
__global__ void k_rows_b(const unsigned* __restrict__ ctrl, const uint2* __restrict__ extra,
                         unsigned* __restrict__ rowc, uint2* __restrict__ rowd) {
    unsigned k_rem = ctrl[6];
    for (unsigned i = blockIdx.x * 256 + threadIdx.x; i < k_rem; i += gridDim.x * 256) {
        unsigned idx = extra[i].x;
        unsigned b = idx >> 15;
        unsigned p = atomicAdd(&rowc[b], 1u);
        if (p < 256u) rowd[(b << 8) + p] = make_uint2(idx & 32767u, extra[i].y);
    }
}

// decode: out[b,:] = b_dec + sum v * WdT[j,:]
__launch_bounds__(256) __global__
void k_decode(const uint2* __restrict__ rowd, const unsigned* __restrict__ rowc,
              const float* __restrict__ WdT, const float* __restrict__ b_dec,
              float* __restrict__ out) {
    __shared__ uint2 e[256];
    int b = blockIdx.x, t = threadIdx.x;
    unsigned c = rowc[b]; if (c > 256u) c = 256u;
    if ((unsigned)t < c) e[t] = rowd[(b << 8) + t];
    __syncthreads();
    float a0 = b_dec[t], a1 = b_dec[t + 256], a2 = b_dec[t + 512];
#pragma unroll 4
    for (unsigned i = 0; i < c; ++i) {
        float v = __uint_as_float(e[i].y);
        const float* w = WdT + (size_t)e[i].x * DDIM;
        a0 = fmaf(v, w[t], a0);
        a1 = fmaf(v, w[t + 256], a1);
        a2 = fmaf(v, w[t + 512], a2);
    }
    float* o = out + (size_t)b * DDIM;
    o[t] = a0; o[t + 256] = a1; o[t + 512] = a2;
}

extern "C" void kernel_launch(void* const* d_in, const int* in_sizes, int n_in,
                              void* d_out, int out_size, void* d_ws, size_t ws_size,
                              hipStream_t stream) {
    const float* x     = (const float*)d_in[0];
    const float* W0    = (const float*)d_in[1];
    const float* b0    = (const float*)d_in[2];
    const float* W1    = (const float*)d_in[3];
    const float* b1    = (const float*)d_in[4];
    const float* Wd    = (const float*)d_in[5];
    const float* b_dec = (const float*)d_in[6];
    float* out = (float*)d_out;

    if (ws_size < WS_NEED) {   // insufficient workspace: fail cleanly
        hipMemsetAsync(d_out, 0, (size_t)out_size * sizeof(float), stream);
        return;
    }

    char* ws = (char*)d_ws;
    short*    XH     = (short*)(ws + OFF_XH);
    short*    XL     = (short*)(ws + OFF_XL);
    short*    W0H    = (short*)(ws + OFF_W0H);
    short*    W0L    = (short*)(ws + OFF_W0L);
    short*    W1H    = (short*)(ws + OFF_W1H);
    short*    W1L    = (short*)(ws + OFF_W1L);
    float*    WdT    = (float*)(ws + OFF_WDT);     // aliases split region
    float*    l0     = (float*)(ws + OFF_L0);
    unsigned* ctrl   = (unsigned*)(ws + OFF_CTRL);
    double*   band_v = (double*)(ws + OFF_CTRL + 65536);
    uint2*    extra  = (uint2*)(ws + OFF_CTRL + 98304);
    unsigned* rowc   = (unsigned*)(ws + OFF_ROWC);
    uint2*    rowd   = (uint2*)(ws + OFF_ROWD);
    uint2*    cand   = (uint2*)(ws + OFF_CAND);

    hipMemsetAsync(ctrl, 0, 6400 * sizeof(unsigned), stream);
    hipMemsetAsync(rowc, 0, BROWS * sizeof(unsigned), stream);

    k_split_x<<<(BROWS * DDIM / 4) / 256, 256, 0, stream>>>(x, b_dec, XH, XL);
    k_split_w<<<(S0N * DDIM / 4) / 256, 256, 0, stream>>>(W0, W0H, W0L);
    k_split_w<<<(DICT * DDIM / 4) / 256, 256, 0, stream>>>(W1, W1H, W1L);

    k_mm<0><<<(S0N / 256) * 16, 512, 0, stream>>>(XH, XL, W0H, W0L, b0, l0, nullptr, nullptr);
    k_mm<1><<<(DICT / 256) * 16, 512, 0, stream>>>(XH, XL, W1H, W1L, b1, l0, cand, ctrl);

    // split region is dead now; WdT aliases it
    k_transpose<<<dim3(DICT / 32, DDIM / 32), 256, 0, stream>>>(Wd, WdT);

    k_hist1<<<1024, 256, 0, stream>>>(cand, ctrl);
    k_scan1<<<1, 256, 0, stream>>>(ctrl);
    k_hist2<<<1024, 256, 0, stream>>>(cand, ctrl);
    k_scan2<<<1, 256, 0, stream>>>(ctrl);
    k_band<<<1024, 256, 0, stream>>>(cand, ctrl);
    k_f64<<<BAND_CAP, 64, 0, stream>>>(x, b_dec, W0, b0, W1, b1, ctrl, band_v);
    k_final<<<1, 256, 0, stream>>>(ctrl, band_v, extra);

    k_rows_a<<<1024, 256, 0, stream>>>(cand, ctrl, rowc, rowd);
    k_rows_b<<<32, 256, 0, stream>>>(ctrl, extra, rowc, rowd);
    k_decode<<<BROWS, 256, 0, stream>>>(rowd, rowc, WdT, b_dec, out);
}